// Round 11
// baseline (781.829 us; speedup 1.0000x reference)
//
#include <hip/hip_runtime.h>
#include <math.h>

typedef unsigned long long u64;
typedef unsigned int u32;

#define BB 8
#define NN 4096
#define MAXK 16
#define BQ 64          // one wave per block
#define BUFSLOTS 16    // per-lane LDS append buffer (8 KB/block)

// spatial grid: 32^3, Gaussian mean on the top Morton boundary.
#define NC 32
#define NCM (1 << 15)
#define GW 0.28f
#define GORIG (-4.48f)
#define GINVW (1.0f / GW)
// Pruning margin: covers |d2_fp - d2_true| (<= ~3e-5) with large slack.
#define MARGIN 2.0e-3f

__device__ __forceinline__ u32 part1by2(u32 x) {
    x &= 0x3FF;
    x = (x | (x << 16)) & 0x030000FF;
    x = (x | (x << 8))  & 0x0300F00F;
    x = (x | (x << 4))  & 0x030C30C3;
    x = (x | (x << 2))  & 0x09249249;
    return x;
}
__device__ __forceinline__ u32 morton3(int cx, int cy, int cz) {
    return (part1by2((u32)cz) << 2) | (part1by2((u32)cy) << 1) | part1by2((u32)cx);
}

// ---- branch-free in-register top-16 machinery (u64 keys, ascending) ----

__device__ __forceinline__ void bitonic16(u64 v[MAXK]) {
#pragma unroll
    for (int k = 2; k <= 16; k <<= 1) {
#pragma unroll
        for (int j = k >> 1; j > 0; j >>= 1) {
#pragma unroll
            for (int i = 0; i < 16; ++i) {
                const int l = i ^ j;
                if (l > i) {
                    const u64 a = v[i], b = v[l];
                    const bool up = ((i & k) == 0);
                    const bool sw = up ? (a > b) : (a < b);
                    v[i] = sw ? b : a;
                    v[l] = sw ? a : b;
                }
            }
        }
    }
}

__device__ __forceinline__ void merge16(u64 list[MAXK], const u64 br[MAXK]) {
    u64 lo[MAXK];
#pragma unroll
    for (int i = 0; i < 16; ++i) {
        const u64 a = list[i], b = br[15 - i];
        lo[i] = a < b ? a : b;
    }
#pragma unroll
    for (int j = 8; j > 0; j >>= 1) {
#pragma unroll
        for (int i = 0; i < 16; ++i) {
            const int l = i ^ j;
            if (l > i) {
                const u64 a = lo[i], b = lo[l];
                const bool sw = a > b;
                lo[i] = sw ? b : a;
                lo[l] = sw ? a : b;
            }
        }
    }
#pragma unroll
    for (int i = 0; i < 16; ++i) list[i] = lo[i];
}

// floorv: append-filter floor (per-lane); wkey = min(list[15], floorv).
__device__ __forceinline__ void flush_buf(u64 list[MAXK], u64& wkey, int& cnt,
                                          const u64 (*buf)[BQ], int lane, u64 floorv) {
    u64 br[MAXK];
#pragma unroll
    for (int i = 0; i < 16; ++i) {
        const u64 v = buf[i][lane];
        br[i] = (i < cnt) ? v : ~0ull;
    }
    bitonic16(br);
    merge16(list, br);
    const u64 l15 = list[15];
    wkey = l15 < floorv ? l15 : floorv;
    cnt = 0;
}

// k = argmax(kvec)+1 (first index wins), gather preds of selected, mean.
__device__ __forceinline__ void write_mean(const float* __restrict__ pb,
                                           const float* __restrict__ kvec,
                                           const u64 list[MAXK],
                                           float* __restrict__ op) {
    float bv = kvec[0]; int bi = 0;
#pragma unroll
    for (int i = 1; i < MAXK; ++i) { const float v = kvec[i]; if (v > bv) { bv = v; bi = i; } }
    const int k = bi + 1;
    float sx = 0.f, sy = 0.f, sz = 0.f;
#pragma unroll
    for (int s = 0; s < MAXK; ++s) {
        if (s < k) {
            const int j = (int)(u32)list[s];
            sx = __fadd_rn(sx, pb[j * 3 + 0]);
            sy = __fadd_rn(sy, pb[j * 3 + 1]);
            sz = __fadd_rn(sz, pb[j * 3 + 2]);
        }
    }
    const float fk = (float)k;
    op[0] = __fdiv_rn(sx, fk);
    op[1] = __fdiv_rn(sy, fk);
    op[2] = __fdiv_rn(sz, fk);
}

// ---- build kernels ----

__global__ __launch_bounds__(256) void knn_zero(u32* __restrict__ p, int n) {
    const int i = blockIdx.x * 256 + (int)threadIdx.x;
    if (i < n) p[i] = 0u;
}

__global__ __launch_bounds__(256) void knn_build(const float* __restrict__ x,
                                                 u32* __restrict__ hist,
                                                 u32* __restrict__ ids) {
    const int g = blockIdx.x * 256 + (int)threadIdx.x;   // 0 .. BB*NN-1
    const int b = g >> 12;
    const float px = x[(size_t)g * 3 + 0];
    const float py = x[(size_t)g * 3 + 1];
    const float pz = x[(size_t)g * 3 + 2];
    int cx = (int)floorf((px - GORIG) * GINVW); cx = cx < 0 ? 0 : (cx > NC - 1 ? NC - 1 : cx);
    int cy = (int)floorf((py - GORIG) * GINVW); cy = cy < 0 ? 0 : (cy > NC - 1 ? NC - 1 : cy);
    int cz = (int)floorf((pz - GORIG) * GINVW); cz = cz < 0 ? 0 : (cz > NC - 1 ? NC - 1 : cz);
    const u32 m = morton3(cx, cy, cz);
    ids[g] = m;
    atomicAdd(&hist[b * NCM + (int)m], 1u);
}

// Exclusive prefix per batch over morton-ordered cells; desc = (count<<32)|start.
__global__ __launch_bounds__(1024) void knn_prefix(const u32* __restrict__ hist,
                                                   u64* __restrict__ desc,
                                                   u32* __restrict__ cursor) {
    const int b = blockIdx.x;
    const int tid = (int)threadIdx.x;
    const int lane = tid & 63, wid = tid >> 6;
    __shared__ u32 wsum[16];
    u32 carry = 0;
    for (int c0 = 0; c0 < NCM; c0 += 4096) {
        const int base = b * NCM + c0 + tid * 4;
        const uint4 v = *(const uint4*)(hist + base);
        const u32 s0 = v.x, s1 = s0 + v.y, s2 = s1 + v.z, s3 = s2 + v.w;
        u32 inc = s3;
#pragma unroll
        for (int off = 1; off < 64; off <<= 1) {
            const u32 n = __shfl_up(inc, off);
            if (lane >= off) inc += n;
        }
        if (lane == 63) wsum[wid] = inc;
        __syncthreads();
        if (wid == 0) {
            u32 s = (lane < 16) ? wsum[lane] : 0u;
#pragma unroll
            for (int off = 1; off < 16; off <<= 1) {
                const u32 n = __shfl_up(s, off);
                if (lane >= off) s += n;
            }
            if (lane < 16) wsum[lane] = s;
        }
        __syncthreads();
        const u32 woff = wid ? wsum[wid - 1] : 0u;
        const u32 tot = wsum[15];
        const u32 excl = carry + woff + (inc - s3);
        const u32 st0 = excl, st1 = excl + s0, st2 = excl + s1, st3 = excl + s2;
        desc[base + 0] = ((u64)v.x << 32) | st0;
        desc[base + 1] = ((u64)v.y << 32) | st1;
        desc[base + 2] = ((u64)v.z << 32) | st2;
        desc[base + 3] = ((u64)v.w << 32) | st3;
        cursor[base + 0] = st0; cursor[base + 1] = st1;
        cursor[base + 2] = st2; cursor[base + 3] = st3;
        __syncthreads();
        carry += tot;
    }
}

// Scatter into morton-sorted order; payload (2x,2y,2z,sq) + orig idx.
__global__ __launch_bounds__(256) void knn_scatter(const float* __restrict__ x,
                                                   const u32* __restrict__ ids,
                                                   u32* __restrict__ cursor,
                                                   float4* __restrict__ tab,
                                                   u32* __restrict__ sorg) {
    const int g = blockIdx.x * 256 + (int)threadIdx.x;
    const int b = g >> 12, i = g & (NN - 1);
    const u32 id = ids[g];
    const u32 p = atomicAdd(&cursor[b * NCM + (int)id], 1u);   // batch-local slot
    const float cx = x[(size_t)g * 3 + 0];
    const float cy = x[(size_t)g * 3 + 1];
    const float cz = x[(size_t)g * 3 + 2];
    const float sq = __fadd_rn(__fadd_rn(__fmul_rn(cx, cx), __fmul_rn(cy, cy)),
                               __fmul_rn(cz, cz));
    tab[(size_t)b * NN + p] = make_float4(__fadd_rn(cx, cx), __fadd_rn(cy, cy),
                                          __fadd_rn(cz, cz), sq);
    sorg[(size_t)b * NN + p] = (u32)i;
}

// ---- main: block-aligned Morton decomposition + streamed sub-boxes ----

// inner2 == 2*inner exactly (doubled coords); d2 bit-identical to reference.
#define STREAM8(SLO, SHI, FLOORV) do {                                        \
    for (int t_ = (SLO); t_ < (SHI); t_ += 8) {                               \
        if (__any((int)(cnt > BUFSLOTS - 8)))                                 \
            flush_buf(list, wkey, cnt, buf, lane, (FLOORV));                  \
        _Pragma("unroll")                                                     \
        for (int u_ = 0; u_ < 8; ++u_) {                                      \
            const int s_ = t_ + u_;                                           \
            if (s_ < (SHI)) {                                                 \
                const float4 c_ = tb[s_];                                     \
                const u32 co_ = sg[s_];                                       \
                const float in2_ = __fadd_rn(__fadd_rn(                       \
                    __fmul_rn(qx, c_.x), __fmul_rn(qy, c_.y)),                \
                    __fmul_rn(qz, c_.z));                                     \
                float d2_ = __fsub_rn(__fadd_rn(qsq, c_.w), in2_);            \
                d2_ = fmaxf(d2_, 0.0f);                                       \
                const u64 key_ = ((u64)__float_as_uint(d2_) << 32)            \
                               | (u64)co_;                                    \
                buf[cnt][lane] = key_;                                        \
                cnt += (key_ < wkey) ? 1 : 0;                                 \
            }                                                                 \
        }                                                                     \
    }                                                                         \
    flush_buf(list, wkey, cnt, buf, lane, (FLOORV));                          \
} while (0)

template <int SIBS>
__global__ __launch_bounds__(BQ) void knn_range(
    const float4* __restrict__ tab, const u32* __restrict__ sorg,
    const u64* __restrict__ desc, u64* __restrict__ keys)
{
    const int lane = (int)threadIdx.x;
    int bid = blockIdx.x;
    const int sib = bid % SIBS; bid /= SIBS;
    const int b = bid >> 6;
    const int wbegin = (bid & 63) * BQ;              // within-batch sorted slot base
    const float4* tb = tab + (size_t)b * NN;
    const u32* sg = sorg + (size_t)b * NN;
    const u64* descb = desc + (size_t)b * NCM;

    const float4 qv = tb[wbegin + lane];             // (2x,2y,2z,sq)
    const float qx = __fmul_rn(0.5f, qv.x);          // exact
    const float qy = __fmul_rn(0.5f, qv.y);
    const float qz = __fmul_rn(0.5f, qv.z);
    const float qsq = qv.w;

    __shared__ u64 buf[BUFSLOTS][BQ];   // [slot][lane] -> 2-way banks (free)
    __shared__ u32 subst[BQ], subcn[BQ];

    // Subset floor: fb = max d2 over the lane's 16-subgroup points.
    // 16 distinct candidates upper-bound the true 16th-NN d2; any true top-16
    // key has d2bits <= fb bits, so the floor below admits all of them.
    float fb = 0.0f;
    const int sgb = wbegin + (lane & 48);
#pragma unroll
    for (int j = 0; j < 16; ++j) {
        const float4 c = tb[sgb + j];
        const float in2 = __fadd_rn(__fadd_rn(
            __fmul_rn(qx, c.x), __fmul_rn(qy, c.y)), __fmul_rn(qz, c.z));
        float d2 = __fsub_rn(__fadd_rn(qsq, c.w), in2);
        d2 = fmaxf(d2, 0.0f);
        fb = fmaxf(fb, d2);
    }
    const u64 floorv = ((u64)__float_as_uint(fb) + 1ull) << 32;

    u64 list[MAXK];
#pragma unroll
    for (int s = 0; s < MAXK; ++s) list[s] = ~0ull;
    u64 wkey = floorv;
    int cnt = 0;

    // Wave bbox + conservative radius (wave-max fb + margin).
    float bxlo = qx, bxhi = qx, bylo = qy, byhi = qy, bzlo = qz, bzhi = qz;
    float r2 = __fadd_rn(fb, MARGIN);
#pragma unroll
    for (int off = 32; off; off >>= 1) {
        bxlo = fminf(bxlo, __shfl_xor(bxlo, off)); bxhi = fmaxf(bxhi, __shfl_xor(bxhi, off));
        bylo = fminf(bylo, __shfl_xor(bylo, off)); byhi = fmaxf(byhi, __shfl_xor(byhi, off));
        bzlo = fminf(bzlo, __shfl_xor(bzlo, off)); bzhi = fmaxf(bzhi, __shfl_xor(bzhi, off));
        r2 = fmaxf(r2, __shfl_xor(r2, off));
    }
    const float r = __fadd_rn(sqrtf(r2), 1.0e-4f);   // ulp slack on sqrt

    int cxlo = (int)floorf((bxlo - r - GORIG) * GINVW);
    int cxhi = (int)floorf((bxhi + r - GORIG) * GINVW);
    int cylo = (int)floorf((bylo - r - GORIG) * GINVW);
    int cyhi = (int)floorf((byhi + r - GORIG) * GINVW);
    int czlo = (int)floorf((bzlo - r - GORIG) * GINVW);
    int czhi = (int)floorf((bzhi + r - GORIG) * GINVW);
    cxlo = cxlo < 0 ? 0 : cxlo; cxhi = cxhi > NC - 1 ? NC - 1 : cxhi;
    cylo = cylo < 0 ? 0 : cylo; cyhi = cyhi > NC - 1 ? NC - 1 : cyhi;
    czlo = czlo < 0 ? 0 : czlo; czhi = czhi > NC - 1 ? NC - 1 : czhi;
    cxlo = __builtin_amdgcn_readfirstlane(cxlo); cxhi = __builtin_amdgcn_readfirstlane(cxhi);
    cylo = __builtin_amdgcn_readfirstlane(cylo); cyhi = __builtin_amdgcn_readfirstlane(cyhi);
    czlo = __builtin_amdgcn_readfirstlane(czlo); czhi = __builtin_amdgcn_readfirstlane(czhi);

    // Decompose the box at multiples of 4 per axis: each sub-box lies in one
    // aligned 4^3 Morton block (64 contiguous codes), so its interval
    // [morton(lo), morton(hi)] overscans at most that block. Sub-boxes are
    // disjoint and live in distinct blocks -> disjoint slot ranges -> the
    // round-robin deal across siblings never duplicates a candidate.
    const int bx0 = cxlo >> 2, px = (cxhi >> 2) - bx0 + 1;
    const int by0 = cylo >> 2, py = (cyhi >> 2) - by0 + 1;
    const int bz0 = czlo >> 2, pz = (czhi >> 2) - bz0 + 1;
    const int P = px * py * pz;

#pragma unroll 1
    for (int p0 = 0; p0 < P; p0 += BQ) {
        const int p = p0 + lane;
        u32 vslo = 0u, vshi = 0u;
        if (p < P) {
            const u32 up = (u32)p;
            const int ix = (int)(up % (u32)px);
            const int iy = (int)((up / (u32)px) % (u32)py);
            const int iz = (int)(up / (u32)(px * py));
            const int xb = (bx0 + ix) << 2, yb = (by0 + iy) << 2, zb = (bz0 + iz) << 2;
            const int pxlo = cxlo > xb ? cxlo : xb, pxhi = cxhi < xb + 3 ? cxhi : xb + 3;
            const int pylo = cylo > yb ? cylo : yb, pyhi = cyhi < yb + 3 ? cyhi : yb + 3;
            const int pzlo = czlo > zb ? czlo : zb, pzhi = czhi < zb + 3 ? czhi : zb + 3;
            const u64 dlo = descb[morton3(pxlo, pylo, pzlo)];
            const u64 dhi = descb[morton3(pxhi, pyhi, pzhi)];
            vslo = (u32)dlo;
            vshi = (u32)dhi + (u32)(dhi >> 32);
        }
        subst[lane] = vslo; subcn[lane] = vshi;
        __builtin_amdgcn_wave_barrier();
        const int nt = (P - p0) < BQ ? (P - p0) : BQ;
#pragma unroll 1
        for (int e = 0; e < nt; ++e) {
            if (((p0 + e) & (SIBS - 1)) != sib) continue;
            const int slo = (int)subst[e];          // uniform LDS broadcast
            const int shi = (int)subcn[e];
            if (slo < shi) {
                STREAM8(slo, shi, floorv);
            }
        }
        __builtin_amdgcn_wave_barrier();
    }
    flush_buf(list, wkey, cnt, buf, lane, floorv);

    // Coalesced key dump; merge maps sorted slot -> orig.
    const size_t qs = (size_t)b * NN + wbegin + lane;
#pragma unroll
    for (int s = 0; s < MAXK; ++s)
        keys[(size_t)(sib * MAXK + s) * (BB * NN) + qs] = list[s];
}

template <int SIBS>
__global__ __launch_bounds__(256) void knn_merge(
    const float* __restrict__ preds, const float* __restrict__ kvec,
    const u64* __restrict__ keys, const u32* __restrict__ sorg,
    float* __restrict__ out)
{
    const int qs = blockIdx.x * 256 + (int)threadIdx.x;   // sorted slot, 0..B*N-1

    u64 list[MAXK];
#pragma unroll
    for (int s = 0; s < MAXK; ++s)
        list[s] = keys[(size_t)s * (BB * NN) + qs];        // coalesced
#pragma unroll 1
    for (int g = 1; g < SIBS; ++g) {
        u64 br[MAXK];
#pragma unroll
        for (int s = 0; s < MAXK; ++s)
            br[s] = keys[(size_t)(g * MAXK + s) * (BB * NN) + qs];
        merge16(list, br);
    }

    const int b = qs >> 12;
    const int qorig = (int)sorg[qs];
    write_mean(preds + (size_t)b * NN * 3, kvec, list,
               out + ((size_t)b * NN + qorig) * 3);
}

// ---- fallback: fused brute force (no workspace), known-good structure ----
__global__ __launch_bounds__(BQ) void knn_brute(
    const float* __restrict__ x, const float* __restrict__ preds,
    const float* __restrict__ kvec, float* __restrict__ out)
{
    const int lane = (int)threadIdx.x;
    const int qg = blockIdx.x % (NN / BQ);
    const int b  = blockIdx.x / (NN / BQ);
    const int qi = qg * BQ + lane;
    const float* xb = x + (size_t)b * NN * 3;
    const float qx = xb[qi * 3 + 0], qy = xb[qi * 3 + 1], qz = xb[qi * 3 + 2];
    const float qsq = __fadd_rn(__fadd_rn(__fmul_rn(qx, qx), __fmul_rn(qy, qy)),
                                __fmul_rn(qz, qz));
    __shared__ u64 buf[BUFSLOTS][BQ];
    u64 list[MAXK];
#pragma unroll
    for (int s = 0; s < MAXK; ++s) list[s] = ~0ull;
    u64 wkey = ~0ull;
    int cnt = 0;
#pragma unroll 1
    for (int t = 0; t < NN; t += 4) {
        if (__any((int)(cnt > BUFSLOTS - 4))) flush_buf(list, wkey, cnt, buf, lane, ~0ull);
#pragma unroll
        for (int u = 0; u < 4; ++u) {
            const int j = t + u;
            const float cx = xb[j * 3 + 0], cy = xb[j * 3 + 1], cz = xb[j * 3 + 2];
            const float csq = __fadd_rn(__fadd_rn(__fmul_rn(cx, cx), __fmul_rn(cy, cy)),
                                        __fmul_rn(cz, cz));
            const float inner = __fadd_rn(
                __fadd_rn(__fmul_rn(qx, cx), __fmul_rn(qy, cy)), __fmul_rn(qz, cz));
            float d2 = __fsub_rn(__fadd_rn(qsq, csq), __fmul_rn(2.0f, inner));
            d2 = fmaxf(d2, 0.0f);
            const u64 key = ((u64)__float_as_uint(d2) << 32) | (u32)j;
            buf[cnt][lane] = key;
            cnt += (key < wkey) ? 1 : 0;
        }
    }
    flush_buf(list, wkey, cnt, buf, lane, ~0ull);
    write_mean(preds + (size_t)b * NN * 3, kvec, list,
               out + ((size_t)b * NN + qi) * 3);
}

extern "C" void kernel_launch(void* const* d_in, const int* in_sizes, int n_in,
                              void* d_out, int out_size, void* d_ws, size_t ws_size,
                              hipStream_t stream) {
    (void)in_sizes; (void)n_in; (void)out_size;
    const float* x     = (const float*)d_in[0];
    const float* preds = (const float*)d_in[1];
    const float* kvec  = (const float*)d_in[2];
    float* out = (float*)d_out;

    // ws layout sized by SIBS: TAB | KEYS | DESC | HIST | CUR | IDS | SORG
    const size_t tab_b  = (size_t)BB * NN * 16;
    const size_t desc_b = (size_t)BB * NCM * 8;
    const size_t hist_b = (size_t)BB * NCM * 4;
    const size_t ids_b  = (size_t)BB * NN * 4;
    auto need = [&](int sibs) {
        return tab_b + (size_t)sibs * MAXK * BB * NN * 8 + desc_b + 2 * hist_b
             + 2 * ids_b;
    };

    int sibs = 0;
    if      (ws_size >= need(8)) sibs = 8;
    else if (ws_size >= need(4)) sibs = 4;

    if (sibs) {
        char* w = (char*)d_ws;
        const size_t keys_b = (size_t)sibs * MAXK * BB * NN * 8;
        float4* tab  = (float4*)w;
        u64* keys    = (u64*)(w + tab_b);
        u64* descp   = (u64*)(w + tab_b + keys_b);
        u32* hist    = (u32*)(w + tab_b + keys_b + desc_b);
        u32* cursor  = (u32*)(w + tab_b + keys_b + desc_b + hist_b);
        u32* ids     = (u32*)(w + tab_b + keys_b + desc_b + 2 * hist_b);
        u32* sorg    = (u32*)(w + tab_b + keys_b + desc_b + 2 * hist_b + ids_b);

        knn_zero<<<(BB * NCM) / 256, 256, 0, stream>>>(hist, BB * NCM);
        knn_build<<<(BB * NN) / 256, 256, 0, stream>>>(x, hist, ids);
        knn_prefix<<<BB, 1024, 0, stream>>>(hist, descp, cursor);
        knn_scatter<<<(BB * NN) / 256, 256, 0, stream>>>(x, ids, cursor, tab, sorg);
        if (sibs == 8) {
            knn_range<8><<<BB * (NN / BQ) * 8, BQ, 0, stream>>>(tab, sorg, descp, keys);
            knn_merge<8><<<(BB * NN) / 256, 256, 0, stream>>>(preds, kvec, keys, sorg, out);
        } else {
            knn_range<4><<<BB * (NN / BQ) * 4, BQ, 0, stream>>>(tab, sorg, descp, keys);
            knn_merge<4><<<(BB * NN) / 256, 256, 0, stream>>>(preds, kvec, keys, sorg, out);
        }
    } else {
        knn_brute<<<BB * (NN / BQ), BQ, 0, stream>>>(x, preds, kvec, out);
    }
}